// Round 8
// baseline (25859.506 us; speedup 1.0000x reference)
//
#include <hip/hip_runtime.h>
#include <stdint.h>

#define B_  16
#define T_  1024
#define H_  1024
#define E_  512
#define V_  256
#define C_  256

typedef __bf16 bf16x8 __attribute__((ext_vector_type(8)));
typedef float  f32x4  __attribute__((ext_vector_type(4)));
typedef unsigned int u32x4 __attribute__((ext_vector_type(4)));
typedef unsigned short u16;
typedef unsigned int   u32;
typedef unsigned long long u64;

__device__ __forceinline__ float bf2f(u16 u) {
  union { unsigned int i; float f; } v; v.i = ((unsigned int)u) << 16; return v.f;
}
__device__ __forceinline__ u16 f2bf(float f) {
  union { float f; unsigned int i; } v; v.f = f;
  unsigned int u = v.i;
  return (u16)((u + 0x7fffu + ((u >> 16) & 1u)) >> 16);  // RNE
}
__device__ __forceinline__ bf16x8 ld_bf8(const u16* p) {
  uint4 v = *(const uint4*)p;
  return __builtin_bit_cast(bf16x8, v);
}
__device__ __forceinline__ float sigm(float x) { return 1.f / (1.f + __expf(-x)); }
__device__ __forceinline__ float tanhfast(float x) {
  // 1 - 2/(e^{2x}+1): exact limits at +-inf, ~1e-7 rel error, all v_exp_f32.
  return 1.f - 2.f / (__expf(2.f * x) + 1.f);
}

// Agent-coherent loads: sc1 policy (what LLVM emits for agent-scope atomics),
// issued as wide ops that pipeline. One waitcnt per volley; sched_barrier
// keeps the tag checks after the wait (rule #18).
#define LOADQ(d, p) \
  asm volatile("global_load_dwordx4 %0, %1, off sc1" : "=&v"(d) : "v"(p) : "memory")
#define LOADD(d, p) \
  asm volatile("global_load_dword %0, %1, off sc1" : "=v"(d) : "v"(p) : "memory")
#define WAITV() do { asm volatile("s_waitcnt vmcnt(0)" ::: "memory"); \
  __builtin_amdgcn_sched_barrier(0); } while (0)

__device__ __forceinline__ u32 tagchk(u32x4 v, u32 tag) {
  return ((v[0] >> 16) ^ tag) | ((v[1] >> 16) ^ tag) |
         ((v[2] >> 16) ^ tag) | ((v[3] >> 16) ^ tag);
}
__device__ __forceinline__ bf16x8 packbf(u32x4 a, u32x4 b) {
  union { u32 w[4]; bf16x8 v; } r;
  r.w[0] = (a[0] & 0xffffu) | (a[1] << 16);
  r.w[1] = (a[2] & 0xffffu) | (a[3] << 16);
  r.w[2] = (b[0] & 0xffffu) | (b[1] << 16);
  r.w[3] = (b[2] & 0xffffu) | (b[3] << 16);
  return r.v;
}

// Fused detect+fetch (1 RTT when producers are ready, the common case):
// optimistic full volley; on tag miss, spin on a CHEAP 32B probe (words 0,7
// of each fragment) and only re-issue the full volley after the probe
// passes. Outer loop exits only on a fully tag-clean volley (backstop).
__device__ __forceinline__ void poll4(const u32* p, u32 tag, bf16x8* out) {
  u32x4 a0,b0,a1,b1,a2,b2,a3,b3;
  for (;;) {
    LOADQ(a0,p);      LOADQ(b0,p+4);
    LOADQ(a1,p+32);   LOADQ(b1,p+36);
    LOADQ(a2,p+64);   LOADQ(b2,p+68);
    LOADQ(a3,p+96);   LOADQ(b3,p+100);
    WAITV();
    const u32 bad = tagchk(a0,tag)|tagchk(b0,tag)|tagchk(a1,tag)|tagchk(b1,tag)
                  | tagchk(a2,tag)|tagchk(b2,tag)|tagchk(a3,tag)|tagchk(b3,tag);
    if (!bad) break;
    for (;;) {                      // probe spin: 32B vs 128B per attempt
      __builtin_amdgcn_s_sleep(2);
      u32 c0,c1,c2,c3,c4,c5,c6,c7;
      LOADD(c0,p);    LOADD(c1,p+7);   LOADD(c2,p+32);  LOADD(c3,p+39);
      LOADD(c4,p+64); LOADD(c5,p+71);  LOADD(c6,p+96);  LOADD(c7,p+103);
      WAITV();
      const u32 pb = ((c0>>16)^tag)|((c1>>16)^tag)|((c2>>16)^tag)|((c3>>16)^tag)
                   | ((c4>>16)^tag)|((c5>>16)^tag)|((c6>>16)^tag)|((c7>>16)^tag);
      if (!pb) break;
    }
  }
  out[0]=packbf(a0,b0); out[1]=packbf(a1,b1);
  out[2]=packbf(a2,b2); out[3]=packbf(a3,b3);
}

// Joint fused fetch of x (4 frags) and h (4 frags) -- one 16-load volley.
__device__ __forceinline__ void poll8(const u32* xp, u32 xtag,
                                      const u32* hp, u32 htag,
                                      bf16x8* ax, bf16x8* ah) {
  u32x4 xa0,xb0,xa1,xb1,xa2,xb2,xa3,xb3;
  u32x4 ha0,hb0,ha1,hb1,ha2,hb2,ha3,hb3;
  for (;;) {
    LOADQ(xa0,xp);      LOADQ(xb0,xp+4);
    LOADQ(xa1,xp+32);   LOADQ(xb1,xp+36);
    LOADQ(xa2,xp+64);   LOADQ(xb2,xp+68);
    LOADQ(xa3,xp+96);   LOADQ(xb3,xp+100);
    LOADQ(ha0,hp);      LOADQ(hb0,hp+4);
    LOADQ(ha1,hp+32);   LOADQ(hb1,hp+36);
    LOADQ(ha2,hp+64);   LOADQ(hb2,hp+68);
    LOADQ(ha3,hp+96);   LOADQ(hb3,hp+100);
    WAITV();
    const u32 bad =
        tagchk(xa0,xtag)|tagchk(xb0,xtag)|tagchk(xa1,xtag)|tagchk(xb1,xtag)
      | tagchk(xa2,xtag)|tagchk(xb2,xtag)|tagchk(xa3,xtag)|tagchk(xb3,xtag)
      | tagchk(ha0,htag)|tagchk(hb0,htag)|tagchk(ha1,htag)|tagchk(hb1,htag)
      | tagchk(ha2,htag)|tagchk(hb2,htag)|tagchk(ha3,htag)|tagchk(hb3,htag);
    if (!bad) break;
    for (;;) {
      __builtin_amdgcn_s_sleep(2);
      u32 c0,c1,c2,c3,c4,c5,c6,c7,d0,d1,d2,d3,d4,d5,d6,d7;
      LOADD(c0,xp);    LOADD(c1,xp+7);  LOADD(c2,xp+32); LOADD(c3,xp+39);
      LOADD(c4,xp+64); LOADD(c5,xp+71); LOADD(c6,xp+96); LOADD(c7,xp+103);
      LOADD(d0,hp);    LOADD(d1,hp+7);  LOADD(d2,hp+32); LOADD(d3,hp+39);
      LOADD(d4,hp+64); LOADD(d5,hp+71); LOADD(d6,hp+96); LOADD(d7,hp+103);
      WAITV();
      const u32 pb =
          ((c0>>16)^xtag)|((c1>>16)^xtag)|((c2>>16)^xtag)|((c3>>16)^xtag)
        | ((c4>>16)^xtag)|((c5>>16)^xtag)|((c6>>16)^xtag)|((c7>>16)^xtag)
        | ((d0>>16)^htag)|((d1>>16)^htag)|((d2>>16)^htag)|((d3>>16)^htag)
        | ((d4>>16)^htag)|((d5>>16)^htag)|((d6>>16)^htag)|((d7>>16)^htag);
      if (!pb) break;
    }
  }
  ax[0]=packbf(xa0,xb0); ax[1]=packbf(xa1,xb1);
  ax[2]=packbf(xa2,xb2); ax[3]=packbf(xa3,xb3);
  ah[0]=packbf(ha0,hb0); ah[1]=packbf(ha1,hb1);
  ah[2]=packbf(ha2,hb2); ah[3]=packbf(ha3,hb3);
}

// load 8 weights as bf16x8 from either f32 or bf16 source (flat element offset)
__device__ __forceinline__ bf16x8 ldw8(const void* W, size_t off, bool f32in) {
  if (f32in) {
    const float* p = (const float*)W + off;
    float4 a = *(const float4*)p;
    float4 b = *(const float4*)(p + 4);
    union { u16 s[8]; bf16x8 v; } r;
    r.s[0]=f2bf(a.x); r.s[1]=f2bf(a.y); r.s[2]=f2bf(a.z); r.s[3]=f2bf(a.w);
    r.s[4]=f2bf(b.x); r.s[5]=f2bf(b.y); r.s[6]=f2bf(b.z); r.s[7]=f2bf(b.w);
    return r.v;
  }
  return ld_bf8((const u16*)W + off);
}
__device__ __forceinline__ float ldb1(const void* p, int i, bool f32in) {
  return f32in ? ((const float*)p)[i] : bf2f(((const u16*)p)[i]);
}

// ---- dtype probe: enc_bih0 uniform(-1/32,1/32): bf16 => exponent<=122 always.
__global__ void probe_k(const u16* __restrict__ s, int* __restrict__ flag) {
  if (threadIdx.x == 0) {
    int cnt = 0;
    for (int i = 0; i < 256; ++i) {
      int e = (s[i] >> 7) & 0xFF;
      if (e >= 124) ++cnt;
    }
    flag[0] = (cnt >= 16) ? 1 : 0;
  }
}

__global__ void cvt_k(const void* __restrict__ src, u16* __restrict__ dst, int n,
                      const int* __restrict__ flagp) {
  int i = blockIdx.x * blockDim.x + threadIdx.x;
  if (i >= n) return;
  if (*flagp) dst[i] = f2bf(((const float*)src)[i]);
  else        dst[i] = ((const u16*)src)[i];
}

// ---------------- persistent seq2seq kernel ----------------
// Tag scheme (global dstep g; enc g=0..1023, dec g=1024..2047): stored word =
// (tag<<16)|bf16. Rings: 8 slots, slot = local_dstep & 7. Initial h zeros:
// zslot (tag 0, memset).
struct PersistArgs {
  const int* tok;
  const u16 *eemb, *demb;                 // normalized bf16 (V,512)
  const void *Wih[4], *Whh[4], *bih[4], *bhh[4];  // idx = phase*2+layer
  const u32 *zslot;                       // (B,H) tagged zeros, tag 0
  u32 *he0, *he1, *hd0, *hd1;             // rings: 8 x (B,H) tagged u32
  u16 *seq;                               // (B,T,H) dec layer1 h (plain bf16)
  u32 *prog;                              // 64 entries, 64 B apart: l1 progress
  const int *dflag;
};

struct PhaseP {
  const void *Wx, *Wh, *bi, *bh;
  const u16* emb;
  const int* tok;
  u32 *r0, *r1;                 // ring bases (this phase)
  const u32 *h0init, *h1init;   // tag gbase slots
  u16* seq;                     // non-null only for dec layer1
  u32 *prog;
  bool f32in, init_c;
  int c0, bid, tid;
  u32 gbase;                    // 0 enc, 1024 dec
};

template<int LAYER>
__device__ void run_phase(const PhaseP& q, f32x4* red4, float* gbuf, float* cbuf,
                          float* bbuf) {
  constexpr int KX = LAYER ? 1024 : 512;
  constexpr int NX = KX / 256;            // frags per wave in x-segment
  constexpr int SLOTN = 16 * 1024;        // u32 per ring slot
  const int tid = q.tid, w = tid >> 6, l = tid & 63;
  const int rr = l & 15, ksub = (l >> 4) * 8;

  // ---- stage weights into registers (held for the whole phase) ----
  bf16x8 BX[4][NX], BH[4][4];
  #pragma unroll
  for (int g = 0; g < 4; ++g) {
    const size_t row = (size_t)(g * 1024 + q.c0 + rr);
    #pragma unroll
    for (int it = 0; it < NX; ++it)
      BX[g][it] = ldw8(q.Wx, row * KX + w * (KX / 8) + it * 32 + ksub, q.f32in);
    #pragma unroll
    for (int it = 0; it < 4; ++it)
      BH[g][it] = ldw8(q.Wh, row * 1024 + w * 128 + it * 32 + ksub, q.f32in);
  }
  if (tid < 64) {
    const int row = (tid >> 4) * 1024 + q.c0 + (tid & 15);
    bbuf[tid] = ldb1(q.bi, row, q.f32in) + ldb1(q.bh, row, q.f32in);
  }
  if (q.init_c && tid < 64) {
    #pragma unroll
    for (int k = 0; k < 4; ++k) cbuf[k * 64 + tid] = 0.f;
  }
  __syncthreads();

  int tok_cur = LAYER ? 0 : q.tok[rr * T_];
  const int s0 = LAYER ? 1 : 0;
  const int s1 = LAYER ? T_ : T_ - 1;

  for (int s = s0; s <= s1; ++s) {
    bf16x8 ax[NX], ah[4];
    u32 pval = 0;
    if (LAYER == 0) {
      // x from emb: static, cached
      const u16* xrow = q.emb + (size_t)tok_cur * 512;
      #pragma unroll
      for (int it = 0; it < NX; ++it)
        ax[it] = ld_bf8(xrow + w * (KX / 8) + it * 32 + ksub);
      // h = own-layer dstep s-1 (tag gbase+s); s==0 -> tagged zeros
      const u32* hslot = (s == 0) ? q.h0init : (q.r0 + ((s - 1) & 7) * SLOTN);
      poll4(hslot + rr * H_ + w * 128 + ksub, q.gbase + (u32)s, ah);
      // overwrite-guard EARLY CHECK: issue the prog load now; its waitcnt
      // sinks to the store-time use, overlapping the RTT with compute.
      if (s >= 8 && tid < 64)
        pval = __hip_atomic_load(&q.prog[tid * 16], __ATOMIC_RELAXED,
                                 __HIP_MEMORY_SCOPE_AGENT);
    } else {
      // x = layer0 dstep s-1 (tag gbase+s); h = own dstep s-2 (tag gbase+s-1)
      const u32* xslot = q.r0 + ((s - 1) & 7) * SLOTN;
      const u32* hslot = (s == 1) ? q.h1init : (q.r1 + ((s - 2) & 7) * SLOTN);
      poll8(xslot + rr * H_ + w * 128 + ksub, q.gbase + (u32)s,
            hslot + rr * H_ + w * 128 + ksub, q.gbase + (u32)(s - 1), ax, ah);
    }
    #pragma unroll
    for (int g = 0; g < 4; ++g) {
      f32x4 acc = {0.f, 0.f, 0.f, 0.f};
      #pragma unroll
      for (int it = 0; it < NX; ++it)
        acc = __builtin_amdgcn_mfma_f32_16x16x32_bf16(ax[it], BX[g][it], acc, 0, 0, 0);
      #pragma unroll
      for (int it = 0; it < 4; ++it)
        acc = __builtin_amdgcn_mfma_f32_16x16x32_bf16(ah[it], BH[g][it], acc, 0, 0, 0);
      red4[(w * 4 + g) * 64 + l] = acc;
    }
    if (LAYER == 0)   // prefetch next step's tokens (pure input)
      tok_cur = q.tok[rr * T_ + ((s + 1 < T_) ? s + 1 : T_ - 1)];
    __syncthreads();
    // publish AFTER barrier: all waves' x loads completed, so layer0 may
    // overwrite the slot this block just consumed.
    if (LAYER == 1 && tid == 0)
      __hip_atomic_store(&q.prog[(q.bid & 63) * 16], q.gbase + (u32)s,
                         __ATOMIC_RELAXED, __HIP_MEMORY_SCOPE_AGENT);
    if (tid < 256) {                     // K-split reduction + bias
      const int g = tid >> 6, ll = tid & 63;
      f32x4 ssum = {0.f, 0.f, 0.f, 0.f};
      #pragma unroll
      for (int w8 = 0; w8 < 8; ++w8) ssum += red4[(w8 * 4 + g) * 64 + ll];
      const int n = ll & 15, mg = (ll >> 4) * 4;
      const float bsum = bbuf[g * 16 + n];
      #pragma unroll
      for (int r = 0; r < 4; ++r) gbuf[(g * 16 + n) * 17 + mg + r] = ssum[r] + bsum;
    }
    __syncthreads();
    if (tid < 64) {                      // LSTM pointwise; 4 cols per thread
      const int m = tid & 15, jg = tid >> 4;
      const u32 stag = LAYER ? (q.gbase + (u32)s) : (q.gbase + (u32)(s + 1));
      u32 wv[4];
      #pragma unroll
      for (int k = 0; k < 4; ++k) {
        const int col = jg * 4 + k;
        const float iv = sigm(gbuf[( 0 + col) * 17 + m]);
        const float fv = sigm(gbuf[(16 + col) * 17 + m]);
        const float gv = tanhfast(gbuf[(32 + col) * 17 + m]);
        const float ov = sigm(gbuf[(48 + col) * 17 + m]);
        const float cn = fv * cbuf[k * 64 + tid] + iv * gv;
        cbuf[k * 64 + tid] = cn;
        wv[k] = (stag << 16) | (u32)f2bf(ov * tanhfast(cn));
      }
      // deferred overwrite guard: slot s&7 holds dstep s-8; all 64 l1 blocks
      // must have consumed it (prog >= gbase+s-7). Early check usually
      // passed; only loop if it hadn't.
      if (LAYER == 0 && s >= 8) {
        const u32 need = q.gbase + (u32)(s - 7);
        if (pval < need) {
          while (__hip_atomic_load(&q.prog[tid * 16], __ATOMIC_RELAXED,
                                   __HIP_MEMORY_SCOPE_AGENT) < need)
            __builtin_amdgcn_s_sleep(2);
        }
      }
      u32* outs = LAYER ? (q.r1 + ((s - 1) & 7) * SLOTN)
                        : (q.r0 + (s & 7) * SLOTN);
      u64* dst = (u64*)(outs + (size_t)m * H_ + q.c0 + jg * 4);
      __hip_atomic_store(dst,     (u64)wv[0] | ((u64)wv[1] << 32),
                         __ATOMIC_RELAXED, __HIP_MEMORY_SCOPE_AGENT);
      __hip_atomic_store(dst + 1, (u64)wv[2] | ((u64)wv[3] << 32),
                         __ATOMIC_RELAXED, __HIP_MEMORY_SCOPE_AGENT);
      if (q.seq) {
        union { u16 s4[4]; u64 q8; } hp;
        #pragma unroll
        for (int k = 0; k < 4; ++k) hp.s4[k] = (u16)(wv[k] & 0xffffu);
        const int t = s - 1;             // only dec layer1 has q.seq
        *(u64*)(q.seq + ((size_t)m * T_ + t) * H_ + q.c0 + jg * 4) = hp.q8;
      }
    }
    // no grid barrier: next iteration's fused tag polls are the sync.
  }
}

__global__ __launch_bounds__(512, 2) void persist_k(PersistArgs P) {
  __shared__ f32x4 red4[32 * 64];   // 32 KB
  __shared__ float gbuf[64 * 17];   // 4.25 KB
  __shared__ float cbuf[4 * 64];    // c-state, carried enc->dec
  __shared__ float bbuf[64];
  const int bid = blockIdx.x, tid = threadIdx.x;
  const int layer = bid >> 6;
  const int c0 = (bid & 63) * 16;
  const bool f32in = (*P.dflag != 0);
  constexpr int SLOTN = 16 * 1024;

  for (int ph = 0; ph < 2; ++ph) {
    PhaseP q;
    const int wi = ph * 2 + layer;
    q.Wx = P.Wih[wi]; q.Wh = P.Whh[wi]; q.bi = P.bih[wi]; q.bh = P.bhh[wi];
    q.emb = ph ? P.demb : P.eemb;
    q.tok = P.tok;
    q.r0 = ph ? P.hd0 : P.he0;
    q.r1 = ph ? P.hd1 : P.he1;
    // enc: tagged zeros (tag 0). dec: enc final states (tag 1024): l0 stored
    // s=1023 -> slot 7; l1 stored s=1024 -> slot 7.
    q.h0init = ph ? (P.he0 + 7 * SLOTN) : P.zslot;
    q.h1init = ph ? (P.he1 + 7 * SLOTN) : P.zslot;
    q.seq = (ph == 1 && layer == 1) ? P.seq : nullptr;
    q.prog = P.prog;
    q.f32in = f32in; q.init_c = (ph == 0);
    q.c0 = c0; q.bid = bid; q.tid = tid;
    q.gbase = ph ? 1024u : 0u;
    if (layer) run_phase<1>(q, red4, gbuf, cbuf, bbuf);
    else       run_phase<0>(q, red4, gbuf, cbuf, bbuf);
  }
}

// logits[b,c,t] = seq[b,t,:] . outW[c,:] + outb[c]; one wave per 16x16 tile.
__global__ __launch_bounds__(256) void logits_k(const u16* __restrict__ A,
                                                const u16* __restrict__ W,
                                                const u16* __restrict__ bias,
                                                void* __restrict__ out,
                                                const int* __restrict__ dflag) {
  const int wid  = blockIdx.x * 4 + (threadIdx.x >> 6);
  const int mt   = wid >> 4;
  const int nt   = wid & 15;
  const int lane = threadIdx.x & 63;
  const int l15  = lane & 15;
  const int quad = lane >> 4;
  const int ko   = quad * 8;
  const u16* arow = A + (size_t)(mt * 16 + l15) * H_;
  const u16* brow = W + (size_t)(nt * 16 + l15) * H_;
  f32x4 acc = {0.f,0.f,0.f,0.f};
  #pragma unroll 4
  for (int kk = 0; kk < H_; kk += 32) {
    acc = __builtin_amdgcn_mfma_f32_16x16x32_bf16(ld_bf8(arow + kk + ko),
                                                  ld_bf8(brow + kk + ko), acc, 0, 0, 0);
  }
  const int c  = nt * 16 + l15;
  const float bv = bf2f(bias[c]);
  const int f32out = *dflag;
  #pragma unroll
  for (int r = 0; r < 4; ++r) {
    const int m = mt * 16 + quad * 4 + r;
    const int b = m >> 10, t = m & 1023;
    const size_t idx = ((size_t)b * C_ + c) * T_ + t;
    const float v = acc[r] + bv;
    if (f32out) ((float*)out)[idx] = v;
    else        ((u16*)out)[idx]   = f2bf(v);
  }
}

extern "C" void kernel_launch(void* const* d_in, const int* in_sizes, int n_in,
                              void* d_out, int out_size, void* d_ws, size_t ws_size,
                              hipStream_t stream) {
  (void)in_sizes; (void)n_in; (void)out_size; (void)ws_size;

  const int* x = (const int*)d_in[0];

  // ---- workspace layout (~36.8 MiB) ----
  char* ws = (char*)d_ws;
  u32* prog   = (u32*)ws;                       // 16 KiB (64 entries, 64 B apart)
  int* dflag  = (int*)(ws + 16384);             // 256 B
  u32* zslot  = (u32*)(ws + 16640);             // 64 KiB tagged zeros
  u32* rings  = (u32*)(ws + 82176);             // 4 rings x 8 slots x 64 KiB = 2 MiB
  char* base  = ws + 2179328;
  size_t ob = 0;
  u16* p_eemb = (u16*)(base + ob); ob += (size_t)V_ * E_ * 2;
  u16* p_demb = (u16*)(base + ob); ob += (size_t)V_ * E_ * 2;
  u16* p_outW = (u16*)(base + ob); ob += (size_t)C_ * H_ * 2;
  u16* p_outb = (u16*)(base + ob); ob += 512;
  u16* seq    = (u16*)(base + ob); ob += (size_t)B_ * T_ * H_ * 2;
  const size_t RING = 8 * (size_t)16 * 1024;    // u32 per ring

  // zero prog + dflag + zslot + rings (tags reset every launch — stale tags
  // from a previous run must never match)
  hipMemsetAsync(ws, 0, 2179328, stream);

  // dtype probe on enc_bih0 (d_in[5])
  probe_k<<<1, 64, 0, stream>>>((const u16*)d_in[5], dflag);

  // normalize embeddings + output head to bf16
  cvt_k<<<(V_ * E_ + 255) / 256, 256, 0, stream>>>(d_in[1], p_eemb, V_ * E_, dflag);
  cvt_k<<<(V_ * E_ + 255) / 256, 256, 0, stream>>>(d_in[2], p_demb, V_ * E_, dflag);
  cvt_k<<<(C_ * H_ + 255) / 256, 256, 0, stream>>>(d_in[19], p_outW, C_ * H_, dflag);
  cvt_k<<<1, 256, 0, stream>>>(d_in[20], p_outb, C_, dflag);

  PersistArgs P;
  P.tok = x; P.eemb = p_eemb; P.demb = p_demb;
  for (int l = 0; l < 4; ++l) {   // input order: enc0, enc1, dec0, dec1
    P.Wih[l] = d_in[3 + 4 * l + 0];
    P.Whh[l] = d_in[3 + 4 * l + 1];
    P.bih[l] = d_in[3 + 4 * l + 2];
    P.bhh[l] = d_in[3 + 4 * l + 3];
  }
  P.zslot = zslot;
  P.he0 = rings + 0 * RING;
  P.he1 = rings + 1 * RING;
  P.hd0 = rings + 2 * RING;
  P.hd1 = rings + 3 * RING;
  P.seq = seq; P.prog = prog; P.dflag = dflag;

  persist_k<<<128, 512, 0, stream>>>(P);

  logits_k<<<4096, 256, 0, stream>>>(seq, p_outW, p_outb, d_out, dflag);
}

// Round 9
// 14177.991 us; speedup vs baseline: 1.8239x; 1.8239x over previous
//
#include <hip/hip_runtime.h>
#include <stdint.h>

#define B_  16
#define T_  1024
#define H_  1024
#define E_  512
#define V_  256
#define C_  256

typedef __bf16 bf16x8 __attribute__((ext_vector_type(8)));
typedef float  f32x4  __attribute__((ext_vector_type(4)));
typedef unsigned int u32x4 __attribute__((ext_vector_type(4)));
typedef unsigned int u32x2 __attribute__((ext_vector_type(2)));
typedef unsigned short u16;
typedef unsigned int   u32;
typedef unsigned long long u64;

__device__ __forceinline__ float bf2f(u16 u) {
  union { unsigned int i; float f; } v; v.i = ((unsigned int)u) << 16; return v.f;
}
__device__ __forceinline__ u16 f2bf(float f) {
  union { float f; unsigned int i; } v; v.f = f;
  unsigned int u = v.i;
  return (u16)((u + 0x7fffu + ((u >> 16) & 1u)) >> 16);  // RNE
}
__device__ __forceinline__ bf16x8 ld_bf8(const u16* p) {
  uint4 v = *(const uint4*)p;
  return __builtin_bit_cast(bf16x8, v);
}
__device__ __forceinline__ float sigm(float x) { return 1.f / (1.f + __expf(-x)); }
__device__ __forceinline__ float tanhfast(float x) {
  return 1.f - 2.f / (__expf(2.f * x) + 1.f);
}

// Agent-coherent (MALL-home, sc1) ops as wide pipelined instructions.
// Inline-asm loads are NOT vmcnt-tracked by the compiler: every use must be
// preceded by WAITV (s_waitcnt vmcnt(0) + sched_barrier, rule #18).
#define LOADQ(d, p) \
  asm volatile("global_load_dwordx4 %0, %1, off sc1" : "=&v"(d) : "v"(p) : "memory")
#define STOREX2(p, d) \
  asm volatile("global_store_dwordx2 %0, %1, off sc1" :: "v"(p), "v"(d) : "memory")
#define STORED(p, d) \
  asm volatile("global_store_dword %0, %1, off sc1" :: "v"(p), "v"(d) : "memory")
#define WAITV() do { asm volatile("s_waitcnt vmcnt(0)" ::: "memory"); \
  __builtin_amdgcn_sched_barrier(0); } while (0)

// Per-wave canary wait: poll 8 producer canaries (packed u32, all lanes load
// the SAME 32B -> broadcast). Release-ordered by producers, so canary==tag
// implies the slot data is visible: the fetch needs no tag backstop.
__device__ __forceinline__ void canwait(const u32* cp, u32 tag) {
  for (;;) {
    u32x4 a, b;
    LOADQ(a, cp); LOADQ(b, cp + 4);
    WAITV();
    const u32 bad = (a[0]^tag)|(a[1]^tag)|(a[2]^tag)|(a[3]^tag)
                  | (b[0]^tag)|(b[1]^tag)|(b[2]^tag)|(b[3]^tag);
    if (!bad) return;
    __builtin_amdgcn_s_sleep(1);
  }
}
__device__ __forceinline__ void canwait2(const u32* cx, u32 tx,
                                         const u32* ch, u32 th) {
  for (;;) {
    u32x4 a, b, c, d;
    LOADQ(a, cx); LOADQ(b, cx + 4);
    LOADQ(c, ch); LOADQ(d, ch + 4);
    WAITV();
    const u32 bad = (a[0]^tx)|(a[1]^tx)|(a[2]^tx)|(a[3]^tx)
                  | (b[0]^tx)|(b[1]^tx)|(b[2]^tx)|(b[3]^tx)
                  | (c[0]^th)|(c[1]^th)|(c[2]^th)|(c[3]^th)
                  | (d[0]^th)|(d[1]^th)|(d[2]^th)|(d[3]^th);
    if (!bad) return;
    __builtin_amdgcn_s_sleep(1);
  }
}

// load 8 weights as bf16x8 from either f32 or bf16 source (flat element offset)
__device__ __forceinline__ bf16x8 ldw8(const void* W, size_t off, bool f32in) {
  if (f32in) {
    const float* p = (const float*)W + off;
    float4 a = *(const float4*)p;
    float4 b = *(const float4*)(p + 4);
    union { u16 s[8]; bf16x8 v; } r;
    r.s[0]=f2bf(a.x); r.s[1]=f2bf(a.y); r.s[2]=f2bf(a.z); r.s[3]=f2bf(a.w);
    r.s[4]=f2bf(b.x); r.s[5]=f2bf(b.y); r.s[6]=f2bf(b.z); r.s[7]=f2bf(b.w);
    return r.v;
  }
  return ld_bf8((const u16*)W + off);
}
__device__ __forceinline__ float ldb1(const void* p, int i, bool f32in) {
  return f32in ? ((const float*)p)[i] : bf2f(((const u16*)p)[i]);
}

// ---- dtype probe: enc_bih0 uniform(-1/32,1/32): bf16 => exponent<=122 always.
__global__ void probe_k(const u16* __restrict__ s, int* __restrict__ flag) {
  if (threadIdx.x == 0) {
    int cnt = 0;
    for (int i = 0; i < 256; ++i) {
      int e = (s[i] >> 7) & 0xFF;
      if (e >= 124) ++cnt;
    }
    flag[0] = (cnt >= 16) ? 1 : 0;
  }
}

__global__ void cvt_k(const void* __restrict__ src, u16* __restrict__ dst, int n,
                      const int* __restrict__ flagp) {
  int i = blockIdx.x * blockDim.x + threadIdx.x;
  if (i >= n) return;
  if (*flagp) dst[i] = f2bf(((const float*)src)[i]);
  else        dst[i] = ((const u16*)src)[i];
}

// ---------------- persistent seq2seq kernel ----------------
// Rings: plain bf16 (B,H) slots, depth 8, slot = dstep & 7. Readiness via
// separate canary arrays can[ring][slot][64] (one u32 per producer block),
// written release-ordered (data stores -> vmcnt drain -> canary store).
// Tags: l0 step s stores canary gbase+s+1 in slot s&7; l1 step s stores
// gbase+s in slot (s-1)&7. Initial zeros: zslot/zcan (memset 0 => tag 0).
struct PersistArgs {
  const int* tok;
  const u16 *eemb, *demb;
  const void *Wih[4], *Whh[4], *bih[4], *bhh[4];  // idx = phase*2+layer
  const u16 *zslot;
  const u32 *zcan;
  u16 *he0, *he1, *hd0, *hd1;   // rings: 8 x (B,H) bf16
  u32 *can;                     // [4 rings][8 slots][64] u32
  u16 *seq;                     // (B,T,H) dec layer1 h (plain bf16)
  u32 *prog;                    // 64 entries, 64 B apart: l1 progress
  const int *dflag;
};

struct PhaseP {
  const void *Wx, *Wh, *bi, *bh;
  const u16* emb;
  const int* tok;
  u16 *r0, *r1;
  u32 *can0, *can1;             // canary bases for r0/r1 rings
  const u16 *h0init, *h1init;
  const u32 *c0init, *c1init;
  u16* seq;
  u32 *prog;
  bool f32in, init_c;
  int c0, bid, tid;
  u32 gbase;
};

template<int LAYER>
__device__ void run_phase(const PhaseP& q, f32x4* red4, float* gbuf, float* cbuf,
                          float* bbuf) {
  constexpr int KX = LAYER ? 1024 : 512;
  constexpr int NX = KX / 256;
  constexpr int SLOTN = 16 * 1024;        // u16 per ring slot
  const int tid = q.tid, w = tid >> 6, l = tid & 63;
  const int rr = l & 15, ksub = (l >> 4) * 8;
  const int myp = q.bid & 63;

  // ---- stage weights into registers (held for the whole phase) ----
  bf16x8 BX[4][NX], BH[4][4];
  #pragma unroll
  for (int g = 0; g < 4; ++g) {
    const size_t row = (size_t)(g * 1024 + q.c0 + rr);
    #pragma unroll
    for (int it = 0; it < NX; ++it)
      BX[g][it] = ldw8(q.Wx, row * KX + w * (KX / 8) + it * 32 + ksub, q.f32in);
    #pragma unroll
    for (int it = 0; it < 4; ++it)
      BH[g][it] = ldw8(q.Wh, row * 1024 + w * 128 + it * 32 + ksub, q.f32in);
  }
  if (tid < 64) {
    const int row = (tid >> 4) * 1024 + q.c0 + (tid & 15);
    bbuf[tid] = ldb1(q.bi, row, q.f32in) + ldb1(q.bh, row, q.f32in);
  }
  if (q.init_c && tid < 64) {
    #pragma unroll
    for (int k = 0; k < 4; ++k) cbuf[k * 64 + tid] = 0.f;
  }
  __syncthreads();

  int tok_cur = LAYER ? 0 : q.tok[rr * T_];
  const int s0 = LAYER ? 1 : 0;
  const int s1 = LAYER ? T_ : T_ - 1;

  for (int s = s0; s <= s1; ++s) {
    bf16x8 ax[NX], ah[4];
    u32 pval = 0;
    if (LAYER == 0) {
      // wave w consumes h cols [128w,128w+128) = producers 8w..8w+7 only
      const u16* hdat = (s == 0) ? q.h0init : (q.r0 + ((s - 1) & 7) * SLOTN);
      const u32* hcan = (s == 0) ? q.c0init : (q.can0 + ((s - 1) & 7) * 64);
      canwait(hcan + 8 * w, q.gbase + (u32)s);
      // x from emb: static, cached
      const u16* xrow = q.emb + (size_t)tok_cur * 512;
      #pragma unroll
      for (int it = 0; it < NX; ++it)
        ax[it] = ld_bf8(xrow + w * (KX / 8) + it * 32 + ksub);
      // un-tagged sc1 fetch (canary release-ordering guarantees validity)
      {
        u32x4 t0,t1,t2,t3;
        const u16* hp = hdat + rr * H_ + w * 128 + ksub;
        LOADQ(t0,hp); LOADQ(t1,hp+32); LOADQ(t2,hp+64); LOADQ(t3,hp+96);
        WAITV();
        ah[0]=__builtin_bit_cast(bf16x8,t0); ah[1]=__builtin_bit_cast(bf16x8,t1);
        ah[2]=__builtin_bit_cast(bf16x8,t2); ah[3]=__builtin_bit_cast(bf16x8,t3);
      }
      // overwrite-guard early check (waitcnt sinks to store-time use)
      if (s >= 8 && tid < 64)
        pval = __hip_atomic_load(&q.prog[tid * 16], __ATOMIC_RELAXED,
                                 __HIP_MEMORY_SCOPE_AGENT);
    } else {
      const u16* xdat = q.r0 + ((s - 1) & 7) * SLOTN;
      const u32* xcan = q.can0 + ((s - 1) & 7) * 64;
      const u16* hdat = (s == 1) ? q.h1init : (q.r1 + ((s - 2) & 7) * SLOTN);
      const u32* hcan = (s == 1) ? q.c1init : (q.can1 + ((s - 2) & 7) * 64);
      canwait2(xcan + 8 * w, q.gbase + (u32)s,
               hcan + 8 * w, q.gbase + (u32)(s - 1));
      u32x4 x0,x1,x2,x3,t0,t1,t2,t3;
      const u16* xp = xdat + rr * H_ + w * 128 + ksub;
      const u16* hp = hdat + rr * H_ + w * 128 + ksub;
      LOADQ(x0,xp); LOADQ(x1,xp+32); LOADQ(x2,xp+64); LOADQ(x3,xp+96);
      LOADQ(t0,hp); LOADQ(t1,hp+32); LOADQ(t2,hp+64); LOADQ(t3,hp+96);
      WAITV();
      ax[0]=__builtin_bit_cast(bf16x8,x0); ax[1]=__builtin_bit_cast(bf16x8,x1);
      ax[2]=__builtin_bit_cast(bf16x8,x2); ax[3]=__builtin_bit_cast(bf16x8,x3);
      ah[0]=__builtin_bit_cast(bf16x8,t0); ah[1]=__builtin_bit_cast(bf16x8,t1);
      ah[2]=__builtin_bit_cast(bf16x8,t2); ah[3]=__builtin_bit_cast(bf16x8,t3);
    }
    #pragma unroll
    for (int g = 0; g < 4; ++g) {
      f32x4 acc = {0.f, 0.f, 0.f, 0.f};
      #pragma unroll
      for (int it = 0; it < NX; ++it)
        acc = __builtin_amdgcn_mfma_f32_16x16x32_bf16(ax[it], BX[g][it], acc, 0, 0, 0);
      #pragma unroll
      for (int it = 0; it < 4; ++it)
        acc = __builtin_amdgcn_mfma_f32_16x16x32_bf16(ah[it], BH[g][it], acc, 0, 0, 0);
      red4[(w * 4 + g) * 64 + l] = acc;
    }
    if (LAYER == 0)
      tok_cur = q.tok[rr * T_ + ((s + 1 < T_) ? s + 1 : T_ - 1)];
    __syncthreads();                     // bar1: all waves' fetch+MFMA done
    // l1 consumed l0 slot (s-1)&7 once every wave's x fetch completed (bar1)
    if (LAYER == 1 && tid == 0)
      __hip_atomic_store(&q.prog[(q.bid & 63) * 16], q.gbase + (u32)s,
                         __ATOMIC_RELAXED, __HIP_MEMORY_SCOPE_AGENT);
    if (tid < 256) {                     // K-split reduction + bias
      const int g = tid >> 6, ll = tid & 63;
      f32x4 ssum = {0.f, 0.f, 0.f, 0.f};
      #pragma unroll
      for (int w8 = 0; w8 < 8; ++w8) ssum += red4[(w8 * 4 + g) * 64 + ll];
      const int n = ll & 15, mg = (ll >> 4) * 4;
      const float bsum = bbuf[g * 16 + n];
      #pragma unroll
      for (int r = 0; r < 4; ++r) gbuf[(g * 16 + n) * 17 + mg + r] = ssum[r] + bsum;
    }
    __syncthreads();                     // bar2: gbuf ready; red4 free to reuse
    if (tid < 64) {                      // LSTM pointwise (wave 0 only)
      const int m = tid & 15, jg = tid >> 4;
      u32x2 hv;
      u16 hs[4];
      #pragma unroll
      for (int k = 0; k < 4; ++k) {
        const int col = jg * 4 + k;
        const float iv = sigm(gbuf[( 0 + col) * 17 + m]);
        const float fv = sigm(gbuf[(16 + col) * 17 + m]);
        const float gv = tanhfast(gbuf[(32 + col) * 17 + m]);
        const float ov = sigm(gbuf[(48 + col) * 17 + m]);
        const float cn = fv * cbuf[k * 64 + tid] + iv * gv;
        cbuf[k * 64 + tid] = cn;
        hs[k] = f2bf(ov * tanhfast(cn));
      }
      hv[0] = (u32)hs[0] | ((u32)hs[1] << 16);
      hv[1] = (u32)hs[2] | ((u32)hs[3] << 16);
      // deferred overwrite guard: slot s&7 holds dstep s-8; all 64 l1 blocks
      // must have consumed it (prog >= gbase+s-7).
      if (LAYER == 0 && s >= 8) {
        const u32 need = q.gbase + (u32)(s - 7);
        if (pval < need) {
          while (__hip_atomic_load(&q.prog[tid * 16], __ATOMIC_RELAXED,
                                   __HIP_MEMORY_SCOPE_AGENT) < need)
            __builtin_amdgcn_s_sleep(2);
        }
      }
      u16* outs = LAYER ? (q.r1 + ((s - 1) & 7) * SLOTN)
                        : (q.r0 + (s & 7) * SLOTN);
      STOREX2(outs + (size_t)m * H_ + q.c0 + jg * 4, hv);
      if (q.seq) {
        union { u16 s4[4]; u64 q8; } hp;
        #pragma unroll
        for (int k = 0; k < 4; ++k) hp.s4[k] = hs[k];
        const int t = s - 1;
        *(u64*)(q.seq + ((size_t)m * T_ + t) * H_ + q.c0 + jg * 4) = hp.q8;
      }
      // RELEASE: drain all wave-0 data stores, then publish canary.
      WAITV();
      if (tid == 0) {
        u32* cslot = LAYER ? (q.can1 + ((s - 1) & 7) * 64)
                           : (q.can0 + (s & 7) * 64);
        const u32 ctag = LAYER ? (q.gbase + (u32)s) : (q.gbase + (u32)(s + 1));
        STORED(cslot + myp, ctag);
      }
    }
    // no top barrier: waves free-run into next step's per-wave canary poll.
  }
}

__global__ __launch_bounds__(512, 2) void persist_k(PersistArgs P) {
  __shared__ f32x4 red4[32 * 64];   // 32 KB
  __shared__ float gbuf[64 * 17];
  __shared__ float cbuf[4 * 64];    // c-state, carried enc->dec
  __shared__ float bbuf[64];
  const int bid = blockIdx.x, tid = threadIdx.x;
  const int layer = bid >> 6;
  const int c0 = (bid & 63) * 16;
  const bool f32in = (*P.dflag != 0);
  constexpr int SLOTN = 16 * 1024;

  for (int ph = 0; ph < 2; ++ph) {
    PhaseP q;
    const int wi = ph * 2 + layer;
    q.Wx = P.Wih[wi]; q.Wh = P.Whh[wi]; q.bi = P.bih[wi]; q.bh = P.bhh[wi];
    q.emb = ph ? P.demb : P.eemb;
    q.tok = P.tok;
    q.r0 = ph ? P.hd0 : P.he0;
    q.r1 = ph ? P.hd1 : P.he1;
    q.can0 = P.can + (ph ? 2 : 0) * 8 * 64;
    q.can1 = P.can + (ph ? 3 : 1) * 8 * 64;
    // enc: zeros (canary 0). dec: enc final states in slot 7, canary 1024.
    q.h0init = ph ? (P.he0 + 7 * SLOTN) : P.zslot;
    q.h1init = ph ? (P.he1 + 7 * SLOTN) : P.zslot;
    q.c0init = ph ? (P.can + (0 * 8 + 7) * 64) : P.zcan;
    q.c1init = ph ? (P.can + (1 * 8 + 7) * 64) : P.zcan;
    q.seq = (ph == 1 && layer == 1) ? P.seq : nullptr;
    q.prog = P.prog;
    q.f32in = f32in; q.init_c = (ph == 0);
    q.c0 = c0; q.bid = bid; q.tid = tid;
    q.gbase = ph ? 1024u : 0u;
    if (layer) run_phase<1>(q, red4, gbuf, cbuf, bbuf);
    else       run_phase<0>(q, red4, gbuf, cbuf, bbuf);
  }
}

// logits[b,c,t] = seq[b,t,:] . outW[c,:] + outb[c]; one wave per 16x16 tile.
__global__ __launch_bounds__(256) void logits_k(const u16* __restrict__ A,
                                                const u16* __restrict__ W,
                                                const u16* __restrict__ bias,
                                                void* __restrict__ out,
                                                const int* __restrict__ dflag) {
  const int wid  = blockIdx.x * 4 + (threadIdx.x >> 6);
  const int mt   = wid >> 4;
  const int nt   = wid & 15;
  const int lane = threadIdx.x & 63;
  const int l15  = lane & 15;
  const int quad = lane >> 4;
  const int ko   = quad * 8;
  const u16* arow = A + (size_t)(mt * 16 + l15) * H_;
  const u16* brow = W + (size_t)(nt * 16 + l15) * H_;
  f32x4 acc = {0.f,0.f,0.f,0.f};
  #pragma unroll 4
  for (int kk = 0; kk < H_; kk += 32) {
    acc = __builtin_amdgcn_mfma_f32_16x16x32_bf16(ld_bf8(arow + kk + ko),
                                                  ld_bf8(brow + kk + ko), acc, 0, 0, 0);
  }
  const int c  = nt * 16 + l15;
  const float bv = bf2f(bias[c]);
  const int f32out = *dflag;
  #pragma unroll
  for (int r = 0; r < 4; ++r) {
    const int m = mt * 16 + quad * 4 + r;
    const int b = m >> 10, t = m & 1023;
    const size_t idx = ((size_t)b * C_ + c) * T_ + t;
    const float v = acc[r] + bv;
    if (f32out) ((float*)out)[idx] = v;
    else        ((u16*)out)[idx]   = f2bf(v);
  }
}

extern "C" void kernel_launch(void* const* d_in, const int* in_sizes, int n_in,
                              void* d_out, int out_size, void* d_ws, size_t ws_size,
                              hipStream_t stream) {
  (void)in_sizes; (void)n_in; (void)out_size; (void)ws_size;

  const int* x = (const int*)d_in[0];

  // ---- workspace layout ----
  char* ws = (char*)d_ws;
  u32* prog   = (u32*)ws;                       // 16 KiB (64 entries, 64 B apart)
  int* dflag  = (int*)(ws + 16384);             // 256 B
  u32* can    = (u32*)(ws + 16640);             // 8 KiB: [4][8][64] u32
  u32* zcan   = (u32*)(ws + 24832);             // 256 B zeros
  u16* zslot  = (u16*)(ws + 25088);             // 32 KiB bf16 zeros
  u16* rings  = (u16*)(ws + 57856);             // 4 rings x 8 slots x 32 KiB = 1 MiB
  char* base  = ws + 1106432;
  size_t ob = 0;
  u16* p_eemb = (u16*)(base + ob); ob += (size_t)V_ * E_ * 2;
  u16* p_demb = (u16*)(base + ob); ob += (size_t)V_ * E_ * 2;
  u16* p_outW = (u16*)(base + ob); ob += (size_t)C_ * H_ * 2;
  u16* p_outb = (u16*)(base + ob); ob += 512;
  u16* seq    = (u16*)(base + ob); ob += (size_t)B_ * T_ * H_ * 2;
  const size_t RING = 8 * (size_t)16 * 1024;    // u16 per ring

  // zero prog+dflag+can+zcan+zslot+rings (canaries reset every launch)
  hipMemsetAsync(ws, 0, 1106432, stream);

  // dtype probe on enc_bih0 (d_in[5])
  probe_k<<<1, 64, 0, stream>>>((const u16*)d_in[5], dflag);

  // normalize embeddings + output head to bf16
  cvt_k<<<(V_ * E_ + 255) / 256, 256, 0, stream>>>(d_in[1], p_eemb, V_ * E_, dflag);
  cvt_k<<<(V_ * E_ + 255) / 256, 256, 0, stream>>>(d_in[2], p_demb, V_ * E_, dflag);
  cvt_k<<<(C_ * H_ + 255) / 256, 256, 0, stream>>>(d_in[19], p_outW, C_ * H_, dflag);
  cvt_k<<<1, 256, 0, stream>>>(d_in[20], p_outb, C_, dflag);

  PersistArgs P;
  P.tok = x; P.eemb = p_eemb; P.demb = p_demb;
  for (int l = 0; l < 4; ++l) {   // input order: enc0, enc1, dec0, dec1
    P.Wih[l] = d_in[3 + 4 * l + 0];
    P.Whh[l] = d_in[3 + 4 * l + 1];
    P.bih[l] = d_in[3 + 4 * l + 2];
    P.bhh[l] = d_in[3 + 4 * l + 3];
  }
  P.zslot = zslot; P.zcan = zcan;
  P.he0 = rings + 0 * RING;
  P.he1 = rings + 1 * RING;
  P.hd0 = rings + 2 * RING;
  P.hd1 = rings + 3 * RING;
  P.can = can;
  P.seq = seq; P.prog = prog; P.dflag = dflag;

  persist_k<<<128, 512, 0, stream>>>(P);

  logits_k<<<4096, 256, 0, stream>>>(seq, p_outW, p_outb, d_out, dflag);
}